// Round 1
// baseline (330.159 us; speedup 1.0000x reference)
//
#include <hip/hip_runtime.h>

typedef unsigned short u16;
typedef short short8 __attribute__((ext_vector_type(8)));
typedef float f32x4 __attribute__((ext_vector_type(4)));

#define P_OUT 29791      // 31^3
#define PPAD  29824      // 233*128
#define NBAT  4
#define NCH   512
#define KDIM  128

// ---- fp32 -> bf16 (RNE) ----
__device__ __forceinline__ u16 f2bf(float f) {
  unsigned u = __builtin_bit_cast(unsigned, f);
  unsigned r = (u + 0x7fffu + ((u >> 16) & 1u)) >> 16;
  return (u16)r;
}
__device__ __forceinline__ unsigned pk2(float a, float b) {
  return (unsigned)f2bf(a) | ((unsigned)f2bf(b) << 16);
}

// ---- prep: x (4,16,32,32,32) -> yb bf16 [4][29824][128] + ysq fp32 ----
// row g = n*PPAD + p ; 16 lanes per row, lane c handles j = c*8 .. c*8+7
// j = c*8 + kd*4 + kh*2 + kw  -> x[n][c][d+kd][h+kh][w+kw]
__global__ void prep_y_kernel(const float* __restrict__ x,
                              u16* __restrict__ yb, float* __restrict__ ysq) {
  const int tid = threadIdx.x;
  const int g = blockIdx.x * 16 + (tid >> 4);
  const int c = tid & 15;
  const int nb = g / PPAD;
  const int pp = g - nb * PPAD;
  float v[8];
  if (pp < P_OUT) {
    const int d = pp / 961;
    const int rem = pp - d * 961;
    const int h = rem / 31;
    const int w = rem - h * 31;
    const float* xb = x + (((size_t)nb * 16 + c) << 15) + d * 1024 + h * 32 + w;
    v[0] = xb[0];    v[1] = xb[1];
    v[2] = xb[32];   v[3] = xb[33];
    v[4] = xb[1024]; v[5] = xb[1025];
    v[6] = xb[1056]; v[7] = xb[1057];
  } else {
#pragma unroll
    for (int i = 0; i < 8; ++i) v[i] = 0.f;
  }
  float s = 0.f;
#pragma unroll
  for (int i = 0; i < 8; ++i) s += v[i] * v[i];
#pragma unroll
  for (int m = 1; m < 16; m <<= 1) s += __shfl_xor(s, m, 64);
  uint4 pk;
  pk.x = pk2(v[0], v[1]); pk.y = pk2(v[2], v[3]);
  pk.z = pk2(v[4], v[5]); pk.w = pk2(v[6], v[7]);
  *(uint4*)(yb + (size_t)g * 128 + c * 8) = pk;
  if (c == 0) ysq[g] = s;
}

// ---- prep: w (512,128) -> wb bf16 + wsq fp32 ----
__global__ void prep_w_kernel(const float* __restrict__ w,
                              u16* __restrict__ wb, float* __restrict__ wsq) {
  const int tid = threadIdx.x;
  const int g = blockIdx.x * 16 + (tid >> 4);  // 0..511
  const int c = tid & 15;
  const float4* wr = (const float4*)(w + g * 128 + c * 8);
  float4 f0 = wr[0], f1 = wr[1];
  float s = f0.x*f0.x + f0.y*f0.y + f0.z*f0.z + f0.w*f0.w
          + f1.x*f1.x + f1.y*f1.y + f1.z*f1.z + f1.w*f1.w;
#pragma unroll
  for (int m = 1; m < 16; m <<= 1) s += __shfl_xor(s, m, 64);
  uint4 pk;
  pk.x = pk2(f0.x, f0.y); pk.y = pk2(f0.z, f0.w);
  pk.z = pk2(f1.x, f1.y); pk.w = pk2(f1.z, f1.w);
  *(uint4*)(wb + g * 128 + c * 8) = pk;
  if (c == 0) wsq[g] = s;
}

// async global->LDS, 16 B per lane, lands at ldsbase + lane*16
#define GLDS(g, l) __builtin_amdgcn_global_load_lds(                         \
    (const __attribute__((address_space(1))) unsigned int*)(g),              \
    (__attribute__((address_space(3))) unsigned int*)(l), 16, 0, 0)

// ---- GEMM + epilogue: out[n][ch][p] = exp(-(ysq[p] - 2*y.w + wsq[ch])) ----
// Tile: 128 ch x 128 p, K=128 in two BK=64 stages. A = w-tile (m=ch),
// B = y-tile (n=p) so C cols (lane&15) are contiguous p -> 64B store segs.
// LDS layout: [row][8 chunks of 16B], chunk swizzled by (row&7) so both the
// global_load_lds staging (lane-linear) and ds_read_b128 frag reads are
// conflict-free.
__global__ void gauss_gemm_kernel(const u16* __restrict__ yb,
                                  const float* __restrict__ ysq,
                                  const u16* __restrict__ wb,
                                  const float* __restrict__ wsq,
                                  float* __restrict__ out) {
  __shared__ __align__(16) u16 As[128 * 64];  // w tile  [ch][k]
  __shared__ __align__(16) u16 Bs[128 * 64];  // y tile  [p][k]

  const int bid = blockIdx.x;
  const int ct = bid & 3;            // 4 ch tiles
  const int pt = (bid >> 2) % 233;   // 233 p tiles
  const int nb = bid / 932;          // 4 batches
  const int p0 = pt * 128;
  const int c0 = ct * 128;

  const int tid = threadIdx.x;
  const int wid = tid >> 6;
  const int lane = tid & 63;
  const int quad = lane >> 4;
  const int col = lane & 15;
  const int wch = wid & 1;   // wave ch-half
  const int wp = wid >> 1;   // wave p-half

  const size_t ybase = ((size_t)nb * PPAD + p0) * 128;

  f32x4 acc[4][4];
#pragma unroll
  for (int i = 0; i < 4; ++i)
#pragma unroll
    for (int j = 0; j < 4; ++j) acc[i][j] = (f32x4){0.f, 0.f, 0.f, 0.f};

#pragma unroll
  for (int it = 0; it < 2; ++it) {
    const int k0 = it * 64;
    // stage: 16KB A + 16KB B, 4 instrs each per wave (1KB per wave-instr)
#pragma unroll
    for (int t = 0; t < 4; ++t) {
      const int Lb = (wid * 4 + t) * 64;      // chunk base (wave-uniform)
      const int L = Lb + lane;                // this lane's LDS chunk
      const int row = L >> 3;
      const int jc = (L & 7) ^ (row & 7);     // unswizzled k-chunk
      GLDS(wb + (size_t)(c0 + row) * 128 + k0 + jc * 8, &As[Lb * 8]);
      GLDS(yb + ybase + (size_t)row * 128 + k0 + jc * 8, &Bs[Lb * 8]);
    }
    __syncthreads();
#pragma unroll
    for (int ks = 0; ks < 2; ++ks) {
      short8 a[4], b[4];
#pragma unroll
      for (int i = 0; i < 4; ++i) {
        const int rowA = wch * 64 + i * 16 + col;
        const int ca = (ks * 4 + quad) ^ (rowA & 7);
        a[i] = *(const short8*)&As[rowA * 64 + ca * 8];
        const int rowB = wp * 64 + i * 16 + col;
        const int cb = (ks * 4 + quad) ^ (rowB & 7);
        b[i] = *(const short8*)&Bs[rowB * 64 + cb * 8];
      }
#pragma unroll
      for (int i = 0; i < 4; ++i)
#pragma unroll
        for (int j = 0; j < 4; ++j)
          acc[i][j] = __builtin_amdgcn_mfma_f32_16x16x32_bf16(a[i], b[j],
                                                              acc[i][j], 0, 0, 0);
    }
    __syncthreads();
  }

  // epilogue: dist = ysq - 2*cross + wsq ; out = exp(-dist)
  float ysv[4];
  int pj[4];
#pragma unroll
  for (int j = 0; j < 4; ++j) {
    pj[j] = p0 + wp * 64 + j * 16 + col;
    ysv[j] = ysq[(size_t)nb * PPAD + pj[j]];
  }
#pragma unroll
  for (int i = 0; i < 4; ++i) {
#pragma unroll
    for (int r = 0; r < 4; ++r) {
      const int ch = c0 + wch * 64 + i * 16 + quad * 4 + r;
      const float wsv = wsq[ch];
      float* ob = out + ((size_t)(nb * NCH + ch)) * P_OUT;
#pragma unroll
      for (int j = 0; j < 4; ++j) {
        if (pj[j] < P_OUT) {
          const float dist = ysv[j] - 2.f * acc[i][j][r] + wsv;
          ob[pj[j]] = __expf(-dist);
        }
      }
    }
  }
}

extern "C" void kernel_launch(void* const* d_in, const int* in_sizes, int n_in,
                              void* d_out, int out_size, void* d_ws, size_t ws_size,
                              hipStream_t stream) {
  const float* x = (const float*)d_in[0];
  const float* w = (const float*)d_in[1];
  float* out = (float*)d_out;
  char* ws = (char*)d_ws;
  // workspace layout (16B-aligned):
  u16* yb   = (u16*)ws;                      // 4*29824*128 bf16 = 61,079,552 B
  float* ysq = (float*)(ws + 61079552);      // 119,296 * 4     =    477,184 B
  u16* wb   = (u16*)(ws + 61556736);         // 512*128 bf16    =    131,072 B
  float* wsq = (float*)(ws + 61687808);      // 512*4           =      2,048 B

  prep_y_kernel<<<7456, 256, 0, stream>>>(x, yb, ysq);   // 119296 rows
  prep_w_kernel<<<32, 256, 0, stream>>>(w, wb, wsq);     // 512 rows
  gauss_gemm_kernel<<<3728, 256, 0, stream>>>(yb, ysq, wb, wsq, out);
}